// Round 2
// baseline (221.564 us; speedup 1.0000x reference)
//
#include <hip/hip_runtime.h>

// RoPE: out[b,s,2k]   = cos(a)*x[b,s,2k] - sin(a)*x[b,s,2k+1]
//       out[b,s,2k+1] = sin(a)*x[b,s,2k] + cos(a)*x[b,s,2k+1]
// with a = pos[s] * theta^(-2k/D).  B=8, S=4096, D=1024, theta=1e4.
//
// Memory-bound elementwise op: one thread per float4 (2 rotation pairs),
// 16 B/lane coalesced loads+stores.
//
// Transcendentals via AMDGPU builtins (CUDA-style __exp2f/__sinf collide
// with glibc math.h in this env):
//   __builtin_amdgcn_exp2f  -> v_exp_f32  (2^x)
//   __builtin_amdgcn_sinf   -> v_sin_f32  (input in REVOLUTIONS, i.e. sin(x*2pi))
//   __builtin_amdgcn_cosf   -> v_cos_f32  (same)
//   __builtin_amdgcn_fractf -> v_fract_f32 (range reduction; exact, period 1)
// Angle is computed directly in revolutions: rev = pos * exp2(coef*k - log2(2pi)).

#define D_DIM   1024
#define D4      (D_DIM / 4)     // float4 per row = 256
#define S_DIM   4096
// coef*k - log2(2*pi):  theta^(-2k/D) / (2*pi) = 2^( -(2k/D)*log2(theta) - log2(2*pi) )
#define LOG2_THETA  13.287712379549449f   // log2(10000)
#define LOG2_2PI     2.651496129472319f   // log2(2*pi)

__global__ __launch_bounds__(256) void rope_kernel(
    const float4* __restrict__ x,
    const int*    __restrict__ pos,
    float4*       __restrict__ out,
    int n4)
{
    int idx = blockIdx.x * blockDim.x + threadIdx.x;
    if (idx >= n4) return;

    // idx layout: [b (3b)] [s (12b)] [j (8b)]  since D4=256, S=4096
    int j = idx & (D4 - 1);          // float4 index within the D row
    int s = (idx >> 8) & (S_DIM - 1);

    float p = (float)pos[s];

    // pairs k0 = 2j, k1 = 2j+1; frequency in revolutions/position
    const float coef = -2.0f / (float)D_DIM * LOG2_THETA;
    float k0 = (float)(2 * j);
    float f0 = __builtin_amdgcn_exp2f(coef * k0 - LOG2_2PI);
    float f1 = __builtin_amdgcn_exp2f(coef * (k0 + 1.0f) - LOG2_2PI);

    // angle in revolutions, reduced to [0,1) (exact: sin/cos have period 1 rev)
    float r0 = __builtin_amdgcn_fractf(p * f0);
    float r1 = __builtin_amdgcn_fractf(p * f1);
    float c0 = __builtin_amdgcn_cosf(r0), s0 = __builtin_amdgcn_sinf(r0);
    float c1 = __builtin_amdgcn_cosf(r1), s1 = __builtin_amdgcn_sinf(r1);

    float4 v = x[idx];
    float4 r;
    r.x = c0 * v.x - s0 * v.y;
    r.y = s0 * v.x + c0 * v.y;
    r.z = c1 * v.z - s1 * v.w;
    r.w = s1 * v.z + c1 * v.w;
    out[idx] = r;
}

extern "C" void kernel_launch(void* const* d_in, const int* in_sizes, int n_in,
                              void* d_out, int out_size, void* d_ws, size_t ws_size,
                              hipStream_t stream) {
    const float4* x   = (const float4*)d_in[0];
    const int*    pos = (const int*)d_in[1];
    float4*       out = (float4*)d_out;

    int n4 = in_sizes[0] / 4;                 // 8,388,608 float4s
    int blocks = (n4 + 255) / 256;            // 32,768 blocks
    rope_kernel<<<blocks, 256, 0, stream>>>(x, pos, out, n4);
}

// Round 5
// 217.508 us; speedup vs baseline: 1.0187x; 1.0187x over previous
//
#include <hip/hip_runtime.h>

// RoPE: out[b,s,2k]   = cos(a)*x[b,s,2k] - sin(a)*x[b,s,2k+1]
//       out[b,s,2k+1] = sin(a)*x[b,s,2k] + cos(a)*x[b,s,2k+1]
// with a = pos[s] * theta^(-2k/D).  B=8, S=4096, D=1024, theta=1e4.
//
// Memory-bound streaming op: one thread per 4 floats (2 rotation pairs),
// 16 B/lane coalesced, nontemporal (zero reuse -> don't pollute L2).
// Round-2 profile: kernel < 80 us (absent from top-5; all top-5 are harness
// 536 MB poison fills at ~6.6 TB/s). bench dur_us ~221 includes harness
// restore+poison serialized on stream.
// Round-4 fix: __builtin_nontemporal_* rejects HIP_vector_type<float,4>
// (a struct) — use a native clang ext_vector_type(4) float instead.
//
// Transcendentals via AMDGPU builtins (CUDA __exp2f/__sinf collide with
// glibc math.h here). v_sin/v_cos take REVOLUTIONS; angle computed directly
// in revolutions: rev = pos * 2^(coef*2j - log2(2pi)), reduced by v_fract
// (exact, period 1). Second pair's freq derived by one multiply:
// f1 = f0 * theta^(-2/D)  (saves one v_exp_f32 per thread).

typedef float f32x4 __attribute__((ext_vector_type(4)));

#define D_DIM   1024
#define D4      (D_DIM / 4)     // f32x4 per row = 256
#define S_DIM   4096
#define LOG2_THETA  13.287712379549449f   // log2(10000)
#define LOG2_2PI     2.651496129472319f   // log2(2*pi)
#define FREQ_RATIO   0.98217188f          // 10000^(-2/1024)

__global__ __launch_bounds__(256) void rope_kernel(
    const f32x4* __restrict__ x,
    const int*   __restrict__ pos,
    f32x4*       __restrict__ out,
    int n4)
{
    int idx = blockIdx.x * blockDim.x + threadIdx.x;
    if (idx >= n4) return;

    // idx layout: [b (3b)] [s (12b)] [j (8b)]  since D4=256, S=4096
    int j = idx & (D4 - 1);          // f32x4 index within the D row
    int s = (idx >> 8) & (S_DIM - 1);

    float p = (float)pos[s];         // uniform per block, L1/L2-cached

    // pair k0 = 2j: freq in revolutions/position; k1 = 2j+1 via one mul
    const float coef = -2.0f / (float)D_DIM * LOG2_THETA;
    float f0 = __builtin_amdgcn_exp2f(coef * (float)(2 * j) - LOG2_2PI);
    float f1 = f0 * FREQ_RATIO;

    // angle in revolutions, reduced to [0,1) (exact: period is 1 rev)
    float r0 = __builtin_amdgcn_fractf(p * f0);
    float r1 = __builtin_amdgcn_fractf(p * f1);
    float c0 = __builtin_amdgcn_cosf(r0), s0 = __builtin_amdgcn_sinf(r0);
    float c1 = __builtin_amdgcn_cosf(r1), s1 = __builtin_amdgcn_sinf(r1);

    f32x4 v = __builtin_nontemporal_load(&x[idx]);
    f32x4 r;
    r.x = c0 * v.x - s0 * v.y;
    r.y = s0 * v.x + c0 * v.y;
    r.z = c1 * v.z - s1 * v.w;
    r.w = s1 * v.z + c1 * v.w;
    __builtin_nontemporal_store(r, &out[idx]);
}

extern "C" void kernel_launch(void* const* d_in, const int* in_sizes, int n_in,
                              void* d_out, int out_size, void* d_ws, size_t ws_size,
                              hipStream_t stream) {
    const f32x4* x   = (const f32x4*)d_in[0];
    const int*   pos = (const int*)d_in[1];
    f32x4*       out = (f32x4*)d_out;

    int n4 = in_sizes[0] / 4;                 // 8,388,608 f32x4s
    int blocks = (n4 + 255) / 256;            // 32,768 blocks
    rope_kernel<<<blocks, 256, 0, stream>>>(x, pos, out, n4);
}